// Round 4
// baseline (356.397 us; speedup 1.0000x reference)
//
#include <hip/hip_runtime.h>

#define H 64
#define H4 16   // H/4 float4s per row

// ws layout (n=100000, e=1600000):
//   s_i (n f32) | s_j (n f32) | count (n i32) | row_start (n i32)
//   | blocksum (128 i32) | csr_src (e i32)

// ---------------------------------------------------------------------------
// Kernel 1: one wave per node — s_i, s_j via shuffle reduce; zero count.
// ---------------------------------------------------------------------------
__global__ void gat_node_kernel(const float* __restrict__ x,
                                const float* __restrict__ w_i,
                                const float* __restrict__ w_j,
                                float* __restrict__ s_i,
                                float* __restrict__ s_j,
                                int* __restrict__ count,
                                int n) {
    int wave = (blockIdx.x * blockDim.x + threadIdx.x) >> 6;
    int lane = threadIdx.x & 63;
    if (wave >= n) return;

    float v = x[(long long)wave * H + lane];
    float a = v * w_i[lane];
    float b = v * w_j[lane];
    #pragma unroll
    for (int off = 32; off > 0; off >>= 1) {
        a += __shfl_down(a, off, 64);
        b += __shfl_down(b, off, 64);
    }
    if (lane == 0) {
        s_i[wave] = a;
        s_j[wave] = b;
        count[wave] = 0;
    }
}

// ---------------------------------------------------------------------------
// Kernel 2: in-degree histogram, int4-vectorized (4 edges/thread).
// ---------------------------------------------------------------------------
__global__ void gat_hist_kernel(const int4* __restrict__ dst4,
                                int* __restrict__ count, int e4) {
    int i = blockIdx.x * blockDim.x + threadIdx.x;
    if (i >= e4) return;
    int4 d = dst4[i];
    atomicAdd(&count[d.x], 1);
    atomicAdd(&count[d.y], 1);
    atomicAdd(&count[d.z], 1);
    atomicAdd(&count[d.w], 1);
}

// ---------------------------------------------------------------------------
// Scan pass 1: 256 thr / block, 4 elems/thread (1024 per block), shuffle scan.
// ---------------------------------------------------------------------------
__global__ void scan1_kernel(const int4* __restrict__ count4,
                             int4* __restrict__ row4,
                             int* __restrict__ blocksum, int n4) {
    int tid = threadIdx.x, lane = tid & 63, w = tid >> 6;
    int i4 = blockIdx.x * 256 + tid;
    int4 c = (i4 < n4) ? count4[i4] : make_int4(0, 0, 0, 0);
    int tsum = c.x + c.y + c.z + c.w;
    int sc = tsum;                       // inclusive wave scan
    #pragma unroll
    for (int off = 1; off < 64; off <<= 1) {
        int v = __shfl_up(sc, off, 64);
        if (lane >= off) sc += v;
    }
    __shared__ int wsum[4];
    if (lane == 63) wsum[w] = sc;
    __syncthreads();
    int wpref = 0;
    for (int j = 0; j < 4; ++j) wpref += (j < w) ? wsum[j] : 0;
    int excl = wpref + sc - tsum;        // exclusive prefix of this thread
    int4 r;
    r.x = excl;
    r.y = r.x + c.x;
    r.z = r.y + c.y;
    r.w = r.z + c.z;
    if (i4 < n4) row4[i4] = r;
    if (tid == 255) blocksum[blockIdx.x] = wpref + sc;  // block total
}

// ---------------------------------------------------------------------------
// Scan pass 2: single block, exclusive scan of block sums (nb <= 128).
// ---------------------------------------------------------------------------
__global__ void scan2_kernel(int* __restrict__ blocksum, int nb) {
    __shared__ int sm[128];
    int tid = threadIdx.x;
    int c = (tid < nb) ? blocksum[tid] : 0;
    sm[tid] = c;
    __syncthreads();
    for (int off = 1; off < 128; off <<= 1) {
        int t = (tid >= off) ? sm[tid - off] : 0;
        __syncthreads();
        sm[tid] += t;
        __syncthreads();
    }
    if (tid < nb) blocksum[tid] = sm[tid] - c;       // exclusive
}

// ---------------------------------------------------------------------------
// Scan pass 3: add block offsets (int4).
// ---------------------------------------------------------------------------
__global__ void scan3_kernel(int4* __restrict__ row4,
                             const int* __restrict__ blocksum, int n4) {
    int i4 = blockIdx.x * blockDim.x + threadIdx.x;
    if (i4 >= n4) return;
    int add = blocksum[i4 >> 8];         // 256 int4 per scan1 block
    int4 r = row4[i4];
    r.x += add; r.y += add; r.z += add; r.w += add;
    row4[i4] = r;
}

// ---------------------------------------------------------------------------
// Kernel 3: scatter src ids into dst-grouped CSR. Mutates row_start -> row_end.
// ---------------------------------------------------------------------------
__global__ void gat_scatter_kernel(const int4* __restrict__ src4,
                                   const int4* __restrict__ dst4,
                                   int* __restrict__ row_start,
                                   int* __restrict__ csr_src, int e4) {
    int i = blockIdx.x * blockDim.x + threadIdx.x;
    if (i >= e4) return;
    int4 s = src4[i];
    int4 d = dst4[i];
    int p;
    p = atomicAdd(&row_start[d.x], 1); csr_src[p] = s.x;
    p = atomicAdd(&row_start[d.y], 1); csr_src[p] = s.y;
    p = atomicAdd(&row_start[d.z], 1); csr_src[p] = s.z;
    p = atomicAdd(&row_start[d.w], 1); csr_src[p] = s.w;
}

// ---------------------------------------------------------------------------
// Kernel 4: one wave per node; 4 edge-groups x 16 lanes x float4.
//   Group g (lanes 16g..16g+15) handles edge slots k = g, g+4, g+8, ...
//   2x unrolled -> up to 8 row gathers in flight per wave.
// ---------------------------------------------------------------------------
__global__ void gat_aggregate_kernel(const float4* __restrict__ x4,
                                     const float* __restrict__ s_i,
                                     const float* __restrict__ s_j,
                                     const int* __restrict__ row_end,
                                     const int* __restrict__ count,
                                     const int* __restrict__ csr_src,
                                     float4* __restrict__ out4, int n) {
    int node = (blockIdx.x * blockDim.x + threadIdx.x) >> 6;
    int lane = threadIdx.x & 63;
    if (node >= n) return;
    int g = lane >> 4;       // edge group 0..3
    int q = lane & 15;       // quarter-row index

    float sii = s_i[node];
    int end = row_end[node];
    int cnt = count[node];
    int start = end - cnt;

    float4 acc = make_float4(0.f, 0.f, 0.f, 0.f);
    float den = 0.f;

    for (int base = 0; base < cnt; base += 64) {
        int rem = cnt - base;
        int prsrc = node;                          // safe default index
        if (lane < rem) prsrc = csr_src[start + base + lane];
        int m = (rem < 64) ? rem : 64;
        int mp = (m + 7) & ~7;
        for (int k = g; k < mp; k += 8) {
            int kb = k + 4;
            int s0 = __shfl(prsrc, k, 64);
            int s1 = __shfl(prsrc, kb & 63, 64);
            float sj0 = s_j[s0];
            float sj1 = s_j[s1];
            float4 xv0 = x4[(long long)s0 * H4 + q];
            float4 xv1 = x4[(long long)s1 * H4 + q];
            float e0 = sii + sj0; e0 = (e0 >= 0.f) ? e0 : 0.01f * e0;
            float e1 = sii + sj1; e1 = (e1 >= 0.f) ? e1 : 0.01f * e1;
            float w0 = (k  < m) ? __expf(e0) : 0.f;
            float w1 = (kb < m) ? __expf(e1) : 0.f;
            acc.x = fmaf(w0, xv0.x, acc.x);
            acc.y = fmaf(w0, xv0.y, acc.y);
            acc.z = fmaf(w0, xv0.z, acc.z);
            acc.w = fmaf(w0, xv0.w, acc.w);
            acc.x = fmaf(w1, xv1.x, acc.x);
            acc.y = fmaf(w1, xv1.y, acc.y);
            acc.z = fmaf(w1, xv1.z, acc.z);
            acc.w = fmaf(w1, xv1.w, acc.w);
            den += w0 + w1;
        }
    }

    // combine the 4 groups (xor over the two group bits)
    #pragma unroll
    for (int off = 16; off <= 32; off <<= 1) {
        acc.x += __shfl_xor(acc.x, off, 64);
        acc.y += __shfl_xor(acc.y, off, 64);
        acc.z += __shfl_xor(acc.z, off, 64);
        acc.w += __shfl_xor(acc.w, off, 64);
        den   += __shfl_xor(den,   off, 64);
    }

    // self-loop
    float sjn = s_j[node];
    float e0 = sii + sjn; e0 = (e0 >= 0.f) ? e0 : 0.01f * e0;
    float w0 = __expf(e0);
    float4 xv = x4[(long long)node * H4 + q];
    acc.x = fmaf(w0, xv.x, acc.x);
    acc.y = fmaf(w0, xv.y, acc.y);
    acc.z = fmaf(w0, xv.z, acc.z);
    acc.w = fmaf(w0, xv.w, acc.w);
    den += w0;

    if (lane < 16) {
        float4 o;
        float inv = 1.f / den;
        o.x = acc.x * inv; o.x = (o.x > 0.f) ? o.x : 0.f;
        o.y = acc.y * inv; o.y = (o.y > 0.f) ? o.y : 0.f;
        o.z = acc.z * inv; o.z = (o.z > 0.f) ? o.z : 0.f;
        o.w = acc.w * inv; o.w = (o.w > 0.f) ? o.w : 0.f;
        out4[(long long)node * H4 + q] = o;
    }
}

extern "C" void kernel_launch(void* const* d_in, const int* in_sizes, int n_in,
                              void* d_out, int out_size, void* d_ws, size_t ws_size,
                              hipStream_t stream) {
    const float* x    = (const float*)d_in[0];
    const int*   edge = (const int*)  d_in[1];
    const float* w_i  = (const float*)d_in[2];
    const float* w_j  = (const float*)d_in[3];

    int n     = in_sizes[0] / H;   // 100000
    int e_cnt = in_sizes[1] / 2;   // 1600000
    const int* src = edge;
    const int* dst = edge + e_cnt;

    float* out = (float*)d_out;

    char* ws = (char*)d_ws;
    float* s_i       = (float*)ws;  ws += (size_t)n * 4;
    float* s_j       = (float*)ws;  ws += (size_t)n * 4;
    int*   count     = (int*)ws;    ws += (size_t)n * 4;
    int*   row_start = (int*)ws;    ws += (size_t)n * 4;
    int*   blocksum  = (int*)ws;    ws += 128 * 4;
    int*   csr_src   = (int*)ws;

    const int BLK = 256;
    int n4 = n / 4;          // 25000 (n divisible by 4)
    int e4 = e_cnt / 4;      // 400000
    int nb = (n + 1023) / 1024;  // 98 scan blocks

    long long node_threads = (long long)n * 64;
    gat_node_kernel<<<(unsigned)((node_threads + BLK - 1) / BLK), BLK, 0, stream>>>(
        x, w_i, w_j, s_i, s_j, count, n);

    gat_hist_kernel<<<(e4 + BLK - 1) / BLK, BLK, 0, stream>>>(
        (const int4*)dst, count, e4);

    scan1_kernel<<<nb, 256, 0, stream>>>(
        (const int4*)count, (int4*)row_start, blocksum, n4);
    scan2_kernel<<<1, 128, 0, stream>>>(blocksum, nb);
    scan3_kernel<<<(n4 + BLK - 1) / BLK, BLK, 0, stream>>>(
        (int4*)row_start, blocksum, n4);

    gat_scatter_kernel<<<(e4 + BLK - 1) / BLK, BLK, 0, stream>>>(
        (const int4*)src, (const int4*)dst, row_start, csr_src, e4);

    gat_aggregate_kernel<<<(unsigned)((node_threads + BLK - 1) / BLK), BLK, 0, stream>>>(
        (const float4*)x, s_i, s_j, row_start, count, csr_src, (float4*)out, n);
}